// Round 2
// baseline (292.326 us; speedup 1.0000x reference)
//
#include <hip/hip_runtime.h>

#define EPSF 1e-6f
#define DD 2048
#define SS 1024
#define BB 2
#define HH 16

// ws float layout: [0,2048) wsum (column sums of Wd); [2048] bbar; [2560,4608) gate

__global__ __launch_bounds__(256) void k_colsum(const float* __restrict__ Wd,
                                                float* __restrict__ wsum) {
    // 256 blocks: dchunk = bid & 7 (8 x 256 columns), echunk = bid >> 3 (32 x 64 rows)
    int dchunk = blockIdx.x & 7;
    int echunk = blockIdx.x >> 3;
    int d = dchunk * 256 + threadIdx.x;
    const float* p = Wd + (size_t)(echunk * 64) * DD + d;
    float acc = 0.f;
#pragma unroll 8
    for (int e = 0; e < 64; ++e) acc += p[(size_t)e * DD];
    atomicAdd(wsum + d, acc);
}

__global__ __launch_bounds__(256) void k_bd(const float* __restrict__ bd,
                                            float* __restrict__ bbar) {
    __shared__ float red[4];
    int t = threadIdx.x;
    float acc = 0.f;
    for (int i = t; i < DD; i += 256) acc += bd[i];
#pragma unroll
    for (int off = 32; off > 0; off >>= 1) acc += __shfl_down(acc, off);
    if ((t & 63) == 0) red[t >> 6] = acc;
    __syncthreads();
    if (t == 0) bbar[0] = (red[0] + red[1] + red[2] + red[3]) * (1.f / DD);
}

__global__ __launch_bounds__(256) void k_gate(const float* __restrict__ x,
                                              const float* __restrict__ wsum,
                                              const float* __restrict__ bbar,
                                              const float* __restrict__ gW,
                                              const float* __restrict__ gb,
                                              float* __restrict__ gate) {
    int p = blockIdx.x;  // position in [0, B*S)
    int t = threadIdx.x;
    const float4* xr = (const float4*)(x + (size_t)p * DD);
    const float4* wr = (const float4*)wsum;
    float acc = 0.f;
#pragma unroll
    for (int k = 0; k < 2; ++k) {
        float4 xv = xr[t + k * 256];
        float4 wv = wr[t + k * 256];
        acc += xv.x * wv.x + xv.y * wv.y + xv.z * wv.z + xv.w * wv.w;
    }
    __shared__ float red[4];
#pragma unroll
    for (int off = 32; off > 0; off >>= 1) acc += __shfl_down(acc, off);
    if ((t & 63) == 0) red[t >> 6] = acc;
    __syncthreads();
    if (t == 0) {
        float dot = (red[0] + red[1] + red[2] + red[3]) * (1.f / DD);
        float he = dot + bbar[0];
        // G = 1 / ((he - z_real + EPS) + i*(-z_imag)), z = 0 + 0.1i
        float a = he + EPSF;
        float den = a * a + 0.01f;
        float reg = a / den;
        float img = 0.1f / den;
        float lin = reg * gW[0] + img * gW[1] + gb[0];  // GATE_SCALE = 1
        gate[p] = 1.f / (1.f + expf(-lin));
    }
}

__global__ __launch_bounds__(256) void k_norm(const float* __restrict__ aw,
                                              const float* __restrict__ gate,
                                              float* __restrict__ out) {
    // one wave per row of 1024 floats; 4 rows per block
    int row = blockIdx.x * 4 + (threadIdx.x >> 6);  // [0, B*H*S)
    int lane = threadIdx.x & 63;
    size_t base = (size_t)row * SS;
    const float4* r = (const float4*)(aw + base);
    float4 v[4];
    float acc = 0.f;
#pragma unroll
    for (int k = 0; k < 4; ++k) {
        v[k] = r[lane + k * 64];
        acc += v[k].x + v[k].y + v[k].z + v[k].w;
    }
#pragma unroll
    for (int off = 1; off < 64; off <<= 1) acc += __shfl_xor(acc, off);
    int s = row & (SS - 1);
    int b = row >> 14;  // row / (H*S), H*S = 16384
    float g = gate[(b << 10) + s];
    float scale = g / (g * acc + EPSF);
    float4* o = (float4*)(out + base);
#pragma unroll
    for (int k = 0; k < 4; ++k) {
        float4 w = v[k];
        w.x *= scale; w.y *= scale; w.z *= scale; w.w *= scale;
        o[lane + k * 64] = w;
    }
}

extern "C" void kernel_launch(void* const* d_in, const int* in_sizes, int n_in,
                              void* d_out, int out_size, void* d_ws, size_t ws_size,
                              hipStream_t stream) {
    const float* x  = (const float*)d_in[0];
    const float* aw = (const float*)d_in[1];
    const float* Wd = (const float*)d_in[2];
    const float* bd = (const float*)d_in[3];
    const float* gW = (const float*)d_in[8];
    const float* gb = (const float*)d_in[9];
    float* out = (float*)d_out;
    float* ws = (float*)d_ws;
    float* wsum = ws;          // 2048 floats
    float* bbar = ws + 2048;   // 1 float
    float* gate = ws + 2560;   // 2048 floats

    hipMemsetAsync(wsum, 0, DD * sizeof(float), stream);
    k_colsum<<<256, 256, 0, stream>>>(Wd, wsum);
    k_bd<<<1, 256, 0, stream>>>(bd, bbar);
    k_gate<<<BB * SS, 256, 0, stream>>>(x, wsum, bbar, gW, gb, gate);
    k_norm<<<8192, 256, 0, stream>>>(aw, gate, out);
}

// Round 4
// 279.308 us; speedup vs baseline: 1.0466x; 1.0466x over previous
//
#include <hip/hip_runtime.h>

#define EPSF 1e-6f
#define DD 2048
#define SS 1024
#define BB 2
#define HH 16

typedef float fx4 __attribute__((ext_vector_type(4)));

// ws float layout: [0,2048) wsum (column sums of Wd); [2560,4608) gate

__global__ __launch_bounds__(256) void k_colsum(const float* __restrict__ Wd,
                                                float* __restrict__ wsum) {
    // 256 blocks: dchunk = bid & 7 (8 x 256 columns), echunk = bid >> 3 (32 x 64 rows)
    int dchunk = blockIdx.x & 7;
    int echunk = blockIdx.x >> 3;
    int d = dchunk * 256 + threadIdx.x;
    const float* p = Wd + (size_t)(echunk * 64) * DD + d;
    float acc = 0.f;
#pragma unroll 8
    for (int e = 0; e < 64; ++e) acc += p[(size_t)e * DD];
    atomicAdd(wsum + d, acc);
}

__global__ __launch_bounds__(256) void k_gate(const float* __restrict__ x,
                                              const float* __restrict__ wsum,
                                              const float* __restrict__ bd,
                                              const float* __restrict__ gW,
                                              const float* __restrict__ gb,
                                              float* __restrict__ gate) {
    int p = blockIdx.x;  // position in [0, B*S)
    int t = threadIdx.x;
    const fx4* xr = (const fx4*)(x + (size_t)p * DD);
    const fx4* wr = (const fx4*)wsum;
    const fx4* br = (const fx4*)bd;
    float accd = 0.f, accb = 0.f;
#pragma unroll
    for (int k = 0; k < 2; ++k) {
        fx4 xv = xr[t + k * 256];
        fx4 wv = wr[t + k * 256];
        fx4 bv = br[t + k * 256];
        accd += xv.x * wv.x + xv.y * wv.y + xv.z * wv.z + xv.w * wv.w;
        accb += bv.x + bv.y + bv.z + bv.w;
    }
    __shared__ float redd[4], redb[4];
#pragma unroll
    for (int off = 32; off > 0; off >>= 1) {
        accd += __shfl_down(accd, off);
        accb += __shfl_down(accb, off);
    }
    if ((t & 63) == 0) { redd[t >> 6] = accd; redb[t >> 6] = accb; }
    __syncthreads();
    if (t == 0) {
        // he = dot(x,wsum)/D + sum(bd)/D
        float he = (redd[0] + redd[1] + redd[2] + redd[3] +
                    redb[0] + redb[1] + redb[2] + redb[3]) * (1.f / DD);
        // G = 1 / ((he + EPS) - 0.1i): Re = a/(a^2+0.01), Im = 0.1/(a^2+0.01)
        float a = he + EPSF;
        float den = a * a + 0.01f;
        float lin = (a * gW[0] + 0.1f * gW[1]) / den + gb[0];  // GATE_SCALE = 1
        gate[p] = 1.f / (1.f + expf(-lin));
    }
}

__global__ __launch_bounds__(256) void k_norm(const float* __restrict__ aw,
                                              const float* __restrict__ gate,
                                              float* __restrict__ out) {
    // one wave per row of 1024 floats; 4 rows per block; streaming (nt) loads/stores
    int row = blockIdx.x * 4 + (threadIdx.x >> 6);  // [0, B*H*S)
    int lane = threadIdx.x & 63;
    size_t base = (size_t)row * SS;
    const fx4* r = (const fx4*)(aw + base);
    fx4 v[4];
    float acc = 0.f;
#pragma unroll
    for (int k = 0; k < 4; ++k) {
        v[k] = __builtin_nontemporal_load(r + lane + k * 64);
        acc += v[k].x + v[k].y + v[k].z + v[k].w;
    }
#pragma unroll
    for (int off = 1; off < 64; off <<= 1) acc += __shfl_xor(acc, off);
    int s = row & (SS - 1);
    int b = row >> 14;  // row / (H*S), H*S = 16384
    float g = gate[(b << 10) + s];
    float scale = g / (g * acc + EPSF);
    fx4* o = (fx4*)(out + base);
#pragma unroll
    for (int k = 0; k < 4; ++k) {
        fx4 w = v[k] * scale;
        __builtin_nontemporal_store(w, o + lane + k * 64);
    }
}

extern "C" void kernel_launch(void* const* d_in, const int* in_sizes, int n_in,
                              void* d_out, int out_size, void* d_ws, size_t ws_size,
                              hipStream_t stream) {
    const float* x  = (const float*)d_in[0];
    const float* aw = (const float*)d_in[1];
    const float* Wd = (const float*)d_in[2];
    const float* bd = (const float*)d_in[3];
    const float* gW = (const float*)d_in[8];
    const float* gb = (const float*)d_in[9];
    float* out = (float*)d_out;
    float* ws = (float*)d_ws;
    float* wsum = ws;          // 2048 floats
    float* gate = ws + 2560;   // 2048 floats

    (void)hipMemsetAsync(wsum, 0, DD * sizeof(float), stream);
    k_colsum<<<256, 256, 0, stream>>>(Wd, wsum);
    k_gate<<<BB * SS, 256, 0, stream>>>(x, wsum, bd, gW, gb, gate);
    k_norm<<<8192, 256, 0, stream>>>(aw, gate, out);
}